// Round 10
// baseline (405.023 us; speedup 1.0000x reference)
//
#include <hip/hip_runtime.h>
#include <hip/hip_bf16.h>
#include <hip/hip_fp8.h>
#include <stdint.h>

#define DIMS 1024
#define STATE 2048
#define BATCH 4
#define SEQ 2048
#define TOKENS 8192   // BATCH*SEQ
#define N1 8192       // fused GEMM1 output columns, INTERLEAVED: col = ch*4 + stream
#define NCHUNK 16
#define CHUNKL (SEQ / NCHUNK)   // 128

typedef __hip_bfloat16 bf16;
typedef unsigned char u8;
typedef unsigned short u16;
typedef __attribute__((ext_vector_type(8))) short bf16x8;
typedef __attribute__((ext_vector_type(4))) float f32x4;
typedef __attribute__((ext_vector_type(16))) float f32x16;
typedef __attribute__((ext_vector_type(2))) long v2i64;

// static fp8 scales: xn*32, W1*256 -> acc/8192 in epilogue
#define XN_SCALE 32.0f
#define W1_SCALE 256.0f
#define INV_SCALE (1.0f / 8192.0f)

__device__ __forceinline__ float sigmoidf_(float x) {
  return 1.0f / (1.0f + __expf(-x));
}

__device__ __forceinline__ u8 to_fp8(float f) {
  __hip_fp8_e4m3 h(f);
  return h.__x;
}

// exact bf16(bits)->f32
__device__ __forceinline__ float b2f(u16 v) {
  union { uint32_t u; float f; } w;
  w.u = ((uint32_t)v) << 16;
  return w.f;
}
// f32 -> bf16 bits (RN via HIP intrinsic)
__device__ __forceinline__ u16 f2bb(float f) {
  union { bf16 b; u16 u; } v;
  v.b = __float2bfloat16(f);
  return v.u;
}

// k-permutation baked into fp8 producers: swap bits 3<->4 of the k index so a
// lane's MFMA operands for two consecutive 16-k slices are 16 CONTIGUOUS bytes.
__device__ __forceinline__ int kperm(int k) {
  return (k & ~24) | ((k & 8) << 1) | ((k & 16) >> 1);
}

// async global->LDS, 16B per lane. LDS dest must be wave-uniform base; HW does base + lane*16.
__device__ __forceinline__ void async_copy16(const void* g, void* l) {
  __builtin_amdgcn_global_load_lds(
      (const __attribute__((address_space(1))) void*)(uintptr_t)g,
      (__attribute__((address_space(3))) void*)(uint32_t)(uintptr_t)l,
      16, 0, 0);
}

// ---- LDS XOR swizzles ----
// 64 B rows (4 x 16B chunks): bank period = row pair.
__device__ __forceinline__ int swz32(int row, int kc) {
  int line = row >> 1;
  int sub = ((row & 1) << 2) | kc;
  return (line << 3) | (sub ^ (line & 7));
}
__device__ __forceinline__ void swz32_dec(int c, int& row, int& kc) {
  int line = c >> 3;
  int sub = (c & 7) ^ (line & 7);
  row = (line << 1) | (sub >> 2);
  kc = sub & 3;
}
// 128 B rows (8 x 16B chunks): one row == one bank period.
__device__ __forceinline__ int swz64(int row, int kc) {
  return (row << 3) | (kc ^ (row & 7));
}
__device__ __forceinline__ void swz64_dec(int c, int& row, int& kc) {
  row = c >> 3;
  kc = (c & 7) ^ (row & 7);
}

// ---------------- weight transpose + cast ----------------
// bf16 variant (W2): W[K][N] -> Wt[N][K]
__global__ __launch_bounds__(256) void transpose_bf16_kernel(
    const float* __restrict__ W, bf16* __restrict__ Wt, int K, int N) {
  __shared__ float tile[32][33];
  int tx = threadIdx.x & 31;
  int ty = threadIdx.x >> 5;
  long col = (long)blockIdx.x * 32 + tx;
  long rowb = (long)blockIdx.y * 32;
#pragma unroll
  for (int i = 0; i < 32; i += 8)
    tile[ty + i][tx] = W[(rowb + ty + i) * N + col];
  __syncthreads();
  long ocol = rowb + tx;
  long orow = (long)blockIdx.x * 32 + ty;
#pragma unroll
  for (int i = 0; i < 32; i += 8)
    Wt[(orow + i) * K + ocol] = __float2bfloat16(tile[tx][ty + i]);
}

// fp8 variant (W1): W[K][N] -> Wt[perm(N)][K] fp8 e4m3 * W1_SCALE, k-permuted.
// Output-channel interleave: fused col n -> dst row = ch*4 + stream, so gemm1's
// epilogue reg-quad holds all 4 streams of one channel.
__global__ __launch_bounds__(256) void transpose_fp8_kernel(
    const float* __restrict__ W, u8* __restrict__ Wt, int K, int N, int stream_base) {
  __shared__ float tile[32][33];
  int tx = threadIdx.x & 31;
  int ty = threadIdx.x >> 5;
  long col = (long)blockIdx.x * 32 + tx;
  long rowb = (long)blockIdx.y * 32;
#pragma unroll
  for (int i = 0; i < 32; i += 8)
    tile[ty + i][tx] = W[(rowb + ty + i) * N + col];
  __syncthreads();
  long ocol = rowb + kperm(tx);  // rowb multiple of 32; permute within group
  long orow = (long)blockIdx.x * 32 + ty;  // original fused channel index
#pragma unroll
  for (int i = 0; i < 32; i += 8) {
    long n = orow + i;
    long dstrow = ((n & 2047) << 2) | (stream_base + (n >> 11));
    Wt[dstrow * K + ocol] = to_fp8(tile[tx][ty + i] * W1_SCALE);
  }
}

// ---------------- split RMSNorm -> fp8 (k-permuted, *XN_SCALE) ----------------
__global__ __launch_bounds__(256) void rmsnorm_kernel(
    const float* __restrict__ x, const float* __restrict__ ls,
    const float* __restrict__ rs, const float* __restrict__ ss,
    u8* __restrict__ xn8) {
  int token = blockIdx.x;
  int tid = threadIdx.x;  // 256 threads, 4 floats each
  const float4* xt = (const float4*)(x + (long)token * DIMS);
  float4 v = xt[tid];
  float s = v.x * v.x + v.y * v.y + v.z * v.z + v.w * v.w;
#pragma unroll
  for (int d = 32; d > 0; d >>= 1) s += __shfl_down(s, d);
  __shared__ float parts[4];
  if ((tid & 63) == 0) parts[tid >> 6] = s;
  __syncthreads();
  int j = tid * 4;
  bool left = j < 512;
  float sum = left ? (parts[0] + parts[1]) : (parts[2] + parts[3]);
  float n = sqrtf(sum * (1.0f / 512.0f));  // ||v||*d^-1/2
  float inv = 1.0f / (n + 1e-8f);
  const float4* sc = (const float4*)(left ? ls : rs);
  float4 g = sc[left ? tid : tid - 128];
  float4 p = ((const float4*)ss)[tid];
  u8 q[4];
  q[0] = to_fp8(v.x * g.x * inv * p.x * XN_SCALE);
  q[1] = to_fp8(v.y * g.y * inv * p.y * XN_SCALE);
  q[2] = to_fp8(v.z * g.z * inv * p.z * XN_SCALE);
  q[3] = to_fp8(v.w * g.w * inv * p.w * XN_SCALE);
  *(uint32_t*)(xn8 + (long)token * DIMS + kperm(j)) = *(uint32_t*)q;
}

// ---------------- GEMM1 fp8 + FUSED GATING EPILOGUE ----------------
// 256x128 block, BK=64, double-buffered, mfma_f32_32x32x16_fp8_fp8, swapped
// operands. Each lane's reg-quad = (Kraw,uraw,gin,gout) of ONE channel ->
// gating computed in-register; outputs:
//   P[token][ch] = packed bf16 (aK, u)   (67 MB; pass-1 + pass-3)
//   G[token][ch] = bf16 g                (33.5 MB; pass-3 only)
__device__ __forceinline__ void g1f8_stage(const u8* __restrict__ A,
                                           const u8* __restrict__ Bt,
                                           long arow0, long brow0, int k0,
                                           int wave, int lane, u8* As, u8* Bs) {
  const int K = DIMS;
#pragma unroll
  for (int i = 0; i < 4; i++) {  // A: 1024 chunks (256 rows x 4)
    int c = (wave * 4 + i) * 64 + lane;
    int row, kc; swz32_dec(c, row, kc);
    async_copy16(A + (arow0 + row) * K + k0 + kc * 16, (char*)As + (wave * 4 + i) * 1024);
  }
#pragma unroll
  for (int i = 0; i < 2; i++) {  // B: 512 chunks (128 rows x 4)
    int c = (wave * 2 + i) * 64 + lane;
    int row, kc; swz32_dec(c, row, kc);
    async_copy16(Bt + (brow0 + row) * K + k0 + kc * 16, (char*)Bs + (wave * 2 + i) * 1024);
  }
}

__global__ __launch_bounds__(256, 2) void gemm1_fp8(
    const u8* __restrict__ A, const u8* __restrict__ Bt,
    uint32_t* __restrict__ P, bf16* __restrict__ G) {
  __shared__ __align__(16) u8 As0[256 * 64], As1[256 * 64];  // 16 KB each
  __shared__ __align__(16) u8 Bs0[128 * 64], Bs1[128 * 64];  // 8 KB each
  int tid = threadIdx.x;
  int lane = tid & 63, wave = tid >> 6;
  int wm = wave & 1, wn = wave >> 1;
  long arow0 = (long)blockIdx.y * 256;
  long brow0 = (long)blockIdx.x * 128;
  int m_lane = lane & 31, q4 = lane >> 5;
  f32x16 acc[4][2] = {};

  g1f8_stage(A, Bt, arow0, brow0, 0, wave, lane, As0, Bs0);
  __syncthreads();  // cold fill, once

  for (int it = 0; it < 16; it += 2) {
    // ---- body A: compute buf0, prefetch buf1 ----
    {
      v2i64 af[2][4], bfr[2][2];
#pragma unroll
      for (int p = 0; p < 2; p++) {
#pragma unroll
        for (int mt = 0; mt < 4; mt++)
          af[p][mt] = *(const v2i64*)(As0 + swz32(wm * 128 + mt * 32 + m_lane, p * 2 + q4) * 16);
#pragma unroll
        for (int nt = 0; nt < 2; nt++)
          bfr[p][nt] = *(const v2i64*)(Bs0 + swz32(wn * 64 + nt * 32 + m_lane, p * 2 + q4) * 16);
      }
      g1f8_stage(A, Bt, arow0, brow0, (it + 1) * 64, wave, lane, As1, Bs1);
#pragma unroll
      for (int p = 0; p < 2; p++)
#pragma unroll
        for (int mt = 0; mt < 4; mt++)
#pragma unroll
          for (int nt = 0; nt < 2; nt++) {
            acc[mt][nt] = __builtin_amdgcn_mfma_f32_32x32x16_fp8_fp8(bfr[p][nt][0], af[p][mt][0], acc[mt][nt], 0, 0, 0);
            acc[mt][nt] = __builtin_amdgcn_mfma_f32_32x32x16_fp8_fp8(bfr[p][nt][1], af[p][mt][1], acc[mt][nt], 0, 0, 0);
          }
      __syncthreads();
    }
    // ---- body B: compute buf1, prefetch buf0 ----
    {
      v2i64 af[2][4], bfr[2][2];
#pragma unroll
      for (int p = 0; p < 2; p++) {
#pragma unroll
        for (int mt = 0; mt < 4; mt++)
          af[p][mt] = *(const v2i64*)(As1 + swz32(wm * 128 + mt * 32 + m_lane, p * 2 + q4) * 16);
#pragma unroll
        for (int nt = 0; nt < 2; nt++)
          bfr[p][nt] = *(const v2i64*)(Bs1 + swz32(wn * 64 + nt * 32 + m_lane, p * 2 + q4) * 16);
      }
      if (it + 2 < 16)
        g1f8_stage(A, Bt, arow0, brow0, (it + 2) * 64, wave, lane, As0, Bs0);
#pragma unroll
      for (int p = 0; p < 2; p++)
#pragma unroll
        for (int mt = 0; mt < 4; mt++)
#pragma unroll
          for (int nt = 0; nt < 2; nt++) {
            acc[mt][nt] = __builtin_amdgcn_mfma_f32_32x32x16_fp8_fp8(bfr[p][nt][0], af[p][mt][0], acc[mt][nt], 0, 0, 0);
            acc[mt][nt] = __builtin_amdgcn_mfma_f32_32x32x16_fp8_fp8(bfr[p][nt][1], af[p][mt][1], acc[mt][nt], 0, 0, 0);
          }
      __syncthreads();
    }
  }
  // Fused gating epilogue. token = arow0+wm*128+mt*32+m_lane;
  // ch = (brow0>>2) + wn*16 + nt*8 + g*2 + q4.
#pragma unroll
  for (int mt = 0; mt < 4; mt++) {
    long row = arow0 + wm * 128 + mt * 32 + m_lane;  // token
#pragma unroll
    for (int nt = 0; nt < 2; nt++) {
#pragma unroll
      for (int g = 0; g < 4; g++) {
        long ch = (brow0 >> 2) + wn * 16 + nt * 8 + g * 2 + q4;
        float kraw = acc[mt][nt][g * 4 + 0] * INV_SCALE;
        float uraw = acc[mt][nt][g * 4 + 1] * INV_SCALE;
        float gin  = acc[mt][nt][g * 4 + 2] * INV_SCALE;
        float gout = acc[mt][nt][g * 4 + 3] * INV_SCALE;
        float aK = sigmoidf_(kraw);
        float u  = uraw * sigmoidf_(gin) * (1.0f - aK);
        float gg = sigmoidf_(gout);
        P[row * STATE + ch] = (uint32_t)f2bb(aK) | ((uint32_t)f2bb(u) << 16);
        G[row * STATE + ch] = __float2bfloat16(gg);
      }
    }
  }
}

// ---------------- GEMM2: 128x128 block, BK=64, DOUBLE-BUFFERED, fused residual ----------------
__device__ __forceinline__ void g2_stage(const bf16* __restrict__ A,
                                         const bf16* __restrict__ Bt,
                                         long arow0, long brow0, int k0, int K,
                                         int wave, int lane, bf16* As, bf16* Bs) {
#pragma unroll
  for (int i = 0; i < 4; i++) {  // 1024 chunks each (128 rows x 64)
    int c = (wave * 4 + i) * 64 + lane;
    int row, kc; swz64_dec(c, row, kc);
    async_copy16(A + (arow0 + row) * K + k0 + kc * 8, (char*)As + (wave * 4 + i) * 1024);
    async_copy16(Bt + (brow0 + row) * K + k0 + kc * 8, (char*)Bs + (wave * 4 + i) * 1024);
  }
}

__global__ __launch_bounds__(256) void gemm2_resid(
    const bf16* __restrict__ A, const bf16* __restrict__ Bt,
    float* __restrict__ C, const float* __restrict__ resid) {
  __shared__ __align__(16) bf16 As0[128 * 64], As1[128 * 64];  // 16 KB each
  __shared__ __align__(16) bf16 Bs0[128 * 64], Bs1[128 * 64];
  const int K = STATE, N = DIMS;
  int tid = threadIdx.x;
  int lane = tid & 63, wave = tid >> 6;
  int wm = wave & 1, wn = wave >> 1;
  long arow0 = (long)blockIdx.y * 128;
  long brow0 = (long)blockIdx.x * 128;
  int r = lane & 15, q = lane >> 4;
  f32x4 acc[4][4] = {};

  g2_stage(A, Bt, arow0, brow0, 0, K, wave, lane, As0, Bs0);
  __syncthreads();

  for (int it = 0; it < 32; it += 2) {
    {
      const bf16x8* AsV = (const bf16x8*)As0;
      const bf16x8* BsV = (const bf16x8*)Bs0;
      bf16x8 af[2][4], bfr[2][4];
#pragma unroll
      for (int ks = 0; ks < 2; ks++) {
#pragma unroll
        for (int mt = 0; mt < 4; mt++) af[ks][mt] = AsV[swz64(wm * 64 + mt * 16 + r, ks * 4 + q)];
#pragma unroll
        for (int nt = 0; nt < 4; nt++) bfr[ks][nt] = BsV[swz64(wn * 64 + nt * 16 + r, ks * 4 + q)];
      }
      g2_stage(A, Bt, arow0, brow0, (it + 1) * 64, K, wave, lane, As1, Bs1);
#pragma unroll
      for (int ks = 0; ks < 2; ks++)
#pragma unroll
        for (int mt = 0; mt < 4; mt++)
#pragma unroll
          for (int nt = 0; nt < 4; nt++)
            acc[mt][nt] = __builtin_amdgcn_mfma_f32_16x16x32_bf16(bfr[ks][nt], af[ks][mt], acc[mt][nt], 0, 0, 0);
      __syncthreads();
    }
    {
      const bf16x8* AsV = (const bf16x8*)As1;
      const bf16x8* BsV = (const bf16x8*)Bs1;
      bf16x8 af[2][4], bfr[2][4];
#pragma unroll
      for (int ks = 0; ks < 2; ks++) {
#pragma unroll
        for (int mt = 0; mt < 4; mt++) af[ks][mt] = AsV[swz64(wm * 64 + mt * 16 + r, ks * 4 + q)];
#pragma unroll
        for (int nt = 0; nt < 4; nt++) bfr[ks][nt] = BsV[swz64(wn * 64 + nt * 16 + r, ks * 4 + q)];
      }
      if (it + 2 < 32)
        g2_stage(A, Bt, arow0, brow0, (it + 2) * 64, K, wave, lane, As0, Bs0);
#pragma unroll
      for (int ks = 0; ks < 2; ks++)
#pragma unroll
        for (int mt = 0; mt < 4; mt++)
#pragma unroll
          for (int nt = 0; nt < 4; nt++)
            acc[mt][nt] = __builtin_amdgcn_mfma_f32_16x16x32_bf16(bfr[ks][nt], af[ks][mt], acc[mt][nt], 0, 0, 0);
      __syncthreads();
    }
  }

#pragma unroll
  for (int mt = 0; mt < 4; mt++) {
    long row = arow0 + wm * 64 + mt * 16 + r;
#pragma unroll
    for (int nt = 0; nt < 4; nt++) {
      long col = brow0 + wn * 64 + nt * 16 + q * 4;
      float4 rv = *(const float4*)(resid + row * N + col);
      float4 ov;
      ov.x = acc[mt][nt][0] + rv.x;
      ov.y = acc[mt][nt][1] + rv.y;
      ov.z = acc[mt][nt][2] + rv.z;
      ov.w = acc[mt][nt][3] + rv.w;
      *(float4*)(C + row * N + col) = ov;
    }
  }
}

// ---------------- chunked gated linear scan over P/G ----------------
// P[token][ch] = (aK_t, u_t) bf16x2.  a_t = aK_{t-1} (a_0 = 1).
// h_t = a_t*h_{t-1} + u_t.  Output: h_t * g_t with g from G.

__global__ __launch_bounds__(256) void chunk_summary_kernel(
    const uint32_t* __restrict__ P, float* __restrict__ carryA,
    float* __restrict__ carryU) {
  int b = blockIdx.x;
  int ch = blockIdx.y * 256 + threadIdx.x;
  int chunk = blockIdx.z;
  int t0 = chunk * CHUNKL;
  const uint32_t* base = P + ((long)b * SEQ) * STATE + ch;
  float a_carry = 1.0f;
  if (chunk != 0) a_carry = b2f((u16)(base[(long)(t0 - 1) * STATE] & 0xffff));
  float A = 1.0f, U = 0.0f;
#pragma unroll 8
  for (int t = t0; t < t0 + CHUNKL; t++) {
    uint32_t w = base[(long)t * STATE];
    float aK = b2f((u16)(w & 0xffff));
    float u  = b2f((u16)(w >> 16));
    A *= a_carry;
    U = a_carry * U + u;
    a_carry = aK;
  }
  int cidx = (b * NCHUNK + chunk) * STATE + ch;
  carryA[cidx] = A;
  carryU[cidx] = U;
}

__global__ __launch_bounds__(256) void carry_scan_kernel(
    const float* __restrict__ carryA, const float* __restrict__ carryU,
    float* __restrict__ carryIn) {
  int idx = blockIdx.x * 256 + threadIdx.x;  // b*STATE + ch
  int b = idx >> 11;
  int ch = idx & 2047;
  float h = 0.0f;
#pragma unroll
  for (int c = 0; c < NCHUNK; c++) {
    int cidx = (b * NCHUNK + c) * STATE + ch;
    carryIn[cidx] = h;
    h = carryA[cidx] * h + carryU[cidx];
  }
}

__global__ __launch_bounds__(256) void scan_chunk_kernel(
    const uint32_t* __restrict__ P, const bf16* __restrict__ G,
    const float* __restrict__ carryIn, bf16* __restrict__ out) {
  int b = blockIdx.x;
  int c0 = blockIdx.y * 32;
  int chunk = blockIdx.z;
  int tstart = chunk * CHUNKL;
  __shared__ float a_s[32][65], u_s[32][65], h_s[32][65];
  int tid = threadIdx.x;
  int lane = tid & 63, wave = tid >> 6;
  int cc = tid & 31;
  int tq = tid >> 5;

  float carryH[8], carryK[8];
#pragma unroll
  for (int i = 0; i < 8; i++) {
    int ch = c0 + wave * 8 + i;
    carryH[i] = carryIn[(b * NCHUNK + chunk) * STATE + ch];
    carryK[i] = (chunk == 0)
                    ? 1.0f
                    : b2f((u16)(P[((long)(b * SEQ + tstart - 1)) * STATE + ch] & 0xffff));
  }

  float g_r[8];
  for (int t0 = tstart; t0 < tstart + CHUNKL; t0 += 64) {
    // load phase: one uint per (ch,t), g from G; lanes contiguous across channels
#pragma unroll
    for (int i = 0; i < 8; i++) {
      int t = tq * 8 + i;
      long idx = ((long)(b * SEQ + t0 + t)) * STATE + c0 + cc;
      uint32_t w = P[idx];
      a_s[cc][t] = b2f((u16)(w & 0xffff));
      u_s[cc][t] = b2f((u16)(w >> 16));
      g_r[i] = __bfloat162float(G[idx]);
    }
    __syncthreads();
#pragma unroll
    for (int i = 0; i < 8; i++) {
      int ch = wave * 8 + i;
      float aK = a_s[ch][lane];
      float u = u_s[ch][lane];
      float a = __shfl_up(aK, 1);
      if (lane == 0) a = carryK[i];
      float A = a, U = u;
#pragma unroll
      for (int d = 1; d < 64; d <<= 1) {
        float Au = __shfl_up(A, d);
        float Uu = __shfl_up(U, d);
        if (lane >= d) { U += A * Uu; A *= Au; }
      }
      float h = U + A * carryH[i];
      carryH[i] = __shfl(h, 63);
      carryK[i] = __shfl(aK, 63);
      h_s[ch][lane] = h;
    }
    __syncthreads();
#pragma unroll
    for (int i = 0; i < 8; i++) {
      int t = tq * 8 + i;
      out[((long)(b * SEQ + t0 + t)) * STATE + c0 + cc] =
          __float2bfloat16(h_s[cc][t] * g_r[i]);
    }
    __syncthreads();
  }
}

extern "C" void kernel_launch(void* const* d_in, const int* in_sizes, int n_in,
                              void* d_out, int out_size, void* d_ws, size_t ws_size,
                              hipStream_t stream) {
  const float* x    = (const float*)d_in[0];
  const float* ls   = (const float*)d_in[1];
  const float* rs   = (const float*)d_in[2];
  const float* ss   = (const float*)d_in[3];
  const float* Wk   = (const float*)d_in[4];
  const float* Wugg = (const float*)d_in[5];
  const float* Wout = (const float*)d_in[6];
  float* out = (float*)d_out;

  // workspace layout (~154 MB)
  char* ws = (char*)d_ws;
  u8*       W1f8 = (u8*)ws;                                     // 8 MB (interleaved rows)
  bf16*     W2t  = (bf16*)(ws + 8388608);                       // 4 MB
  u8*       xn8  = (u8*)(ws + 8388608 + 4194304);               // 8 MB
  uint32_t* P    = (uint32_t*)(ws + 20971520);                  // [8192][2048] u32 = 67 MB
  bf16*     G    = (bf16*)(ws + 20971520 + 67108864);           // [8192][2048] bf16 = 33.5 MB
  bf16*     sco  = (bf16*)(ws + 20971520 + 67108864 + 33554432);// [8192][2048] bf16 = 33.5 MB
  // carry buffers (3 x 512 KB) overlay xn8: xn8 is dead after gemm1.
  float* carryA  = (float*)xn8;
  float* carryU  = carryA + BATCH * NCHUNK * STATE;
  float* carryIn = carryU + BATCH * NCHUNK * STATE;

  // W1 -> fp8 (scaled, k-permuted, channel-interleaved rows), W2 -> bf16
  transpose_fp8_kernel<<<dim3(STATE / 32, DIMS / 32), 256, 0, stream>>>(
      Wk, W1f8, DIMS, STATE, 0);
  transpose_fp8_kernel<<<dim3(3 * STATE / 32, DIMS / 32), 256, 0, stream>>>(
      Wugg, W1f8, DIMS, 3 * STATE, 1);
  transpose_bf16_kernel<<<dim3(DIMS / 32, STATE / 32), 256, 0, stream>>>(Wout, W2t, STATE, DIMS);

  rmsnorm_kernel<<<TOKENS, 256, 0, stream>>>(x, ls, rs, ss, xn8);

  gemm1_fp8<<<dim3(N1 / 128, TOKENS / 256), 256, 0, stream>>>(xn8, W1f8, P, G);

  chunk_summary_kernel<<<dim3(BATCH, STATE / 256, NCHUNK), 256, 0, stream>>>(
      P, carryA, carryU);
  carry_scan_kernel<<<dim3(BATCH * STATE / 256), 256, 0, stream>>>(
      carryA, carryU, carryIn);
  scan_chunk_kernel<<<dim3(BATCH, STATE / 32, NCHUNK), 256, 0, stream>>>(
      P, G, carryIn, sco);

  gemm2_resid<<<dim3(DIMS / 128, TOKENS / 128), 256, 0, stream>>>(
      sco, W2t, out, x);
}

// Round 11
// 384.671 us; speedup vs baseline: 1.0529x; 1.0529x over previous
//
#include <hip/hip_runtime.h>
#include <hip/hip_bf16.h>
#include <hip/hip_fp8.h>
#include <stdint.h>

#define DIMS 1024
#define STATE 2048
#define BATCH 4
#define SEQ 2048
#define TOKENS 8192   // BATCH*SEQ
#define N1 8192       // fused GEMM1 output columns, INTERLEAVED: col = ch*4 + stream
#define NCHUNK 16
#define CHUNKL (SEQ / NCHUNK)   // 128

typedef __hip_bfloat16 bf16;
typedef unsigned char u8;
typedef unsigned short u16;
typedef __attribute__((ext_vector_type(4))) float f32x4;
typedef __attribute__((ext_vector_type(16))) float f32x16;
typedef __attribute__((ext_vector_type(2))) long v2i64;

// static fp8 scales: GEMM1 xn*32, W1*256; GEMM2 sco*32, W2*256 -> acc/8192
#define XN_SCALE 32.0f
#define W1_SCALE 256.0f
#define H_SCALE  32.0f
#define W2_SCALE 256.0f
#define INV_SCALE (1.0f / 8192.0f)

__device__ __forceinline__ float sigmoidf_(float x) {
  return 1.0f / (1.0f + __expf(-x));
}

__device__ __forceinline__ u8 to_fp8(float f) {
  __hip_fp8_e4m3 h(f);
  return h.__x;
}

// exact bf16(bits)->f32
__device__ __forceinline__ float b2f(u16 v) {
  union { uint32_t u; float f; } w;
  w.u = ((uint32_t)v) << 16;
  return w.f;
}

// k-permutation baked into fp8 producers: swap bits 3<->4 of the k index so a
// lane's MFMA operands for two consecutive 16-k slices are 16 CONTIGUOUS bytes.
__device__ __forceinline__ int kperm(int k) {
  return (k & ~24) | ((k & 8) << 1) | ((k & 16) >> 1);
}

// async global->LDS, 16B per lane. LDS dest must be wave-uniform base; HW does base + lane*16.
__device__ __forceinline__ void async_copy16(const void* g, void* l) {
  __builtin_amdgcn_global_load_lds(
      (const __attribute__((address_space(1))) void*)(uintptr_t)g,
      (__attribute__((address_space(3))) void*)(uint32_t)(uintptr_t)l,
      16, 0, 0);
}

// ---- LDS XOR swizzle for 64 B rows (4 x 16B chunks): bank period = row pair ----
__device__ __forceinline__ int swz32(int row, int kc) {
  int line = row >> 1;
  int sub = ((row & 1) << 2) | kc;
  return (line << 3) | (sub ^ (line & 7));
}
__device__ __forceinline__ void swz32_dec(int c, int& row, int& kc) {
  int line = c >> 3;
  int sub = (c & 7) ^ (line & 7);
  row = (line << 1) | (sub >> 2);
  kc = sub & 3;
}

// ---------------- weight transpose + fp32->fp8 cast ----------------
// W[K][N] -> Wt[perm(N)][K] fp8 e4m3 * scale, k-permuted along K.
// interleave=1 (W1): fused col n -> dst row = ch*4 + (stream_base + n>>11).
// interleave=0 (W2): dst row = n.
__global__ __launch_bounds__(256) void transpose_fp8_kernel(
    const float* __restrict__ W, u8* __restrict__ Wt, int K, int N,
    int stream_base, int interleave, float scale) {
  __shared__ float tile[32][33];
  int tx = threadIdx.x & 31;
  int ty = threadIdx.x >> 5;
  long col = (long)blockIdx.x * 32 + tx;
  long rowb = (long)blockIdx.y * 32;
#pragma unroll
  for (int i = 0; i < 32; i += 8)
    tile[ty + i][tx] = W[(rowb + ty + i) * N + col];
  __syncthreads();
  long ocol = rowb + kperm(tx);  // rowb multiple of 32; permute within group
  long orow = (long)blockIdx.x * 32 + ty;  // original output-channel index
#pragma unroll
  for (int i = 0; i < 32; i += 8) {
    long n = orow + i;
    long dstrow = interleave ? (((n & 2047) << 2) | (stream_base + (n >> 11))) : n;
    Wt[dstrow * K + ocol] = to_fp8(tile[tx][ty + i] * scale);
  }
}

// ---------------- split RMSNorm -> fp8 (k-permuted, *XN_SCALE) ----------------
__global__ __launch_bounds__(256) void rmsnorm_kernel(
    const float* __restrict__ x, const float* __restrict__ ls,
    const float* __restrict__ rs, const float* __restrict__ ss,
    u8* __restrict__ xn8) {
  int token = blockIdx.x;
  int tid = threadIdx.x;  // 256 threads, 4 floats each
  const float4* xt = (const float4*)(x + (long)token * DIMS);
  float4 v = xt[tid];
  float s = v.x * v.x + v.y * v.y + v.z * v.z + v.w * v.w;
#pragma unroll
  for (int d = 32; d > 0; d >>= 1) s += __shfl_down(s, d);
  __shared__ float parts[4];
  if ((tid & 63) == 0) parts[tid >> 6] = s;
  __syncthreads();
  int j = tid * 4;
  bool left = j < 512;
  float sum = left ? (parts[0] + parts[1]) : (parts[2] + parts[3]);
  float n = sqrtf(sum * (1.0f / 512.0f));  // ||v||*d^-1/2
  float inv = 1.0f / (n + 1e-8f);
  const float4* sc = (const float4*)(left ? ls : rs);
  float4 g = sc[left ? tid : tid - 128];
  float4 p = ((const float4*)ss)[tid];
  u8 q[4];
  q[0] = to_fp8(v.x * g.x * inv * p.x * XN_SCALE);
  q[1] = to_fp8(v.y * g.y * inv * p.y * XN_SCALE);
  q[2] = to_fp8(v.z * g.z * inv * p.z * XN_SCALE);
  q[3] = to_fp8(v.w * g.w * inv * p.w * XN_SCALE);
  *(uint32_t*)(xn8 + (long)token * DIMS + kperm(j)) = *(uint32_t*)q;
}

// ---------------- GEMM1 fp8: 256x128 block, BK=64, DOUBLE-BUFFERED (R9 form) -------
// mfma_f32_32x32x16_fp8_fp8, swapped operands: D col=token, D row=interleaved
// channel col -> 8B packed bf16 stores into C1 (raw pre-activations).
__device__ __forceinline__ void g1f8_stage(const u8* __restrict__ A,
                                           const u8* __restrict__ Bt,
                                           long arow0, long brow0, int k0,
                                           int wave, int lane, u8* As, u8* Bs) {
  const int K = DIMS;
#pragma unroll
  for (int i = 0; i < 4; i++) {  // A: 1024 chunks (256 rows x 4)
    int c = (wave * 4 + i) * 64 + lane;
    int row, kc; swz32_dec(c, row, kc);
    async_copy16(A + (arow0 + row) * K + k0 + kc * 16, (char*)As + (wave * 4 + i) * 1024);
  }
#pragma unroll
  for (int i = 0; i < 2; i++) {  // B: 512 chunks (128 rows x 4)
    int c = (wave * 2 + i) * 64 + lane;
    int row, kc; swz32_dec(c, row, kc);
    async_copy16(Bt + (brow0 + row) * K + k0 + kc * 16, (char*)Bs + (wave * 2 + i) * 1024);
  }
}

__global__ __launch_bounds__(256, 2) void gemm1_fp8(
    const u8* __restrict__ A, const u8* __restrict__ Bt, bf16* __restrict__ C) {
  __shared__ __align__(16) u8 As0[256 * 64], As1[256 * 64];  // 16 KB each
  __shared__ __align__(16) u8 Bs0[128 * 64], Bs1[128 * 64];  // 8 KB each
  int tid = threadIdx.x;
  int lane = tid & 63, wave = tid >> 6;
  int wm = wave & 1, wn = wave >> 1;
  long arow0 = (long)blockIdx.y * 256;
  long brow0 = (long)blockIdx.x * 128;
  int m_lane = lane & 31, q4 = lane >> 5;
  f32x16 acc[4][2] = {};

  g1f8_stage(A, Bt, arow0, brow0, 0, wave, lane, As0, Bs0);
  __syncthreads();  // cold fill, once

  for (int it = 0; it < 16; it += 2) {
    {
      v2i64 af[2][4], bfr[2][2];
#pragma unroll
      for (int p = 0; p < 2; p++) {
#pragma unroll
        for (int mt = 0; mt < 4; mt++)
          af[p][mt] = *(const v2i64*)(As0 + swz32(wm * 128 + mt * 32 + m_lane, p * 2 + q4) * 16);
#pragma unroll
        for (int nt = 0; nt < 2; nt++)
          bfr[p][nt] = *(const v2i64*)(Bs0 + swz32(wn * 64 + nt * 32 + m_lane, p * 2 + q4) * 16);
      }
      g1f8_stage(A, Bt, arow0, brow0, (it + 1) * 64, wave, lane, As1, Bs1);
#pragma unroll
      for (int p = 0; p < 2; p++)
#pragma unroll
        for (int mt = 0; mt < 4; mt++)
#pragma unroll
          for (int nt = 0; nt < 2; nt++) {
            acc[mt][nt] = __builtin_amdgcn_mfma_f32_32x32x16_fp8_fp8(bfr[p][nt][0], af[p][mt][0], acc[mt][nt], 0, 0, 0);
            acc[mt][nt] = __builtin_amdgcn_mfma_f32_32x32x16_fp8_fp8(bfr[p][nt][1], af[p][mt][1], acc[mt][nt], 0, 0, 0);
          }
      __syncthreads();
    }
    {
      v2i64 af[2][4], bfr[2][2];
#pragma unroll
      for (int p = 0; p < 2; p++) {
#pragma unroll
        for (int mt = 0; mt < 4; mt++)
          af[p][mt] = *(const v2i64*)(As1 + swz32(wm * 128 + mt * 32 + m_lane, p * 2 + q4) * 16);
#pragma unroll
        for (int nt = 0; nt < 2; nt++)
          bfr[p][nt] = *(const v2i64*)(Bs1 + swz32(wn * 64 + nt * 32 + m_lane, p * 2 + q4) * 16);
      }
      if (it + 2 < 16)
        g1f8_stage(A, Bt, arow0, brow0, (it + 2) * 64, wave, lane, As0, Bs0);
#pragma unroll
      for (int p = 0; p < 2; p++)
#pragma unroll
        for (int mt = 0; mt < 4; mt++)
#pragma unroll
          for (int nt = 0; nt < 2; nt++) {
            acc[mt][nt] = __builtin_amdgcn_mfma_f32_32x32x16_fp8_fp8(bfr[p][nt][0], af[p][mt][0], acc[mt][nt], 0, 0, 0);
            acc[mt][nt] = __builtin_amdgcn_mfma_f32_32x32x16_fp8_fp8(bfr[p][nt][1], af[p][mt][1], acc[mt][nt], 0, 0, 0);
          }
      __syncthreads();
    }
  }
#pragma unroll
  for (int mt = 0; mt < 4; mt++) {
    long row = arow0 + wm * 128 + mt * 32 + m_lane;  // token
#pragma unroll
    for (int nt = 0; nt < 2; nt++) {
#pragma unroll
      for (int g = 0; g < 4; g++) {
        long col = brow0 + wn * 64 + nt * 32 + g * 8 + q4 * 4;  // interleaved channel col
        bf16 tmp[4];
#pragma unroll
        for (int j = 0; j < 4; j++)
          tmp[j] = __float2bfloat16(acc[mt][nt][g * 4 + j] * INV_SCALE);
        *(uint2*)(C + row * N1 + col) = *(uint2*)tmp;
      }
    }
  }
}

// ---------------- GEMM2 fp8: 128x128 block, BK=64, DOUBLE-BUFFERED, fused residual ----
// A = sco8[token][kperm(ch)] fp8*H_SCALE, B = W2f8[y][kperm(k)] fp8*W2_SCALE.
// 4 waves x (64x64) via 32x32x16 fp8 MFMA, swapped operands -> D row = y-col,
// reg-quad = 4 consecutive y-cols -> float4 residual epilogue.
__device__ __forceinline__ void g2f8_stage(const u8* __restrict__ A,
                                           const u8* __restrict__ Bt,
                                           long arow0, long brow0, int k0,
                                           int wave, int lane, u8* As, u8* Bs) {
  const int K = STATE;
#pragma unroll
  for (int i = 0; i < 2; i++) {  // A: 512 chunks (128 rows x 4)
    int c = (wave * 2 + i) * 64 + lane;
    int row, kc; swz32_dec(c, row, kc);
    async_copy16(A + (arow0 + row) * K + k0 + kc * 16, (char*)As + (wave * 2 + i) * 1024);
  }
#pragma unroll
  for (int i = 0; i < 2; i++) {  // B: 512 chunks
    int c = (wave * 2 + i) * 64 + lane;
    int row, kc; swz32_dec(c, row, kc);
    async_copy16(Bt + (brow0 + row) * K + k0 + kc * 16, (char*)Bs + (wave * 2 + i) * 1024);
  }
}

__global__ __launch_bounds__(256) void gemm2_fp8(
    const u8* __restrict__ A, const u8* __restrict__ Bt,
    float* __restrict__ C, const float* __restrict__ resid) {
  __shared__ __align__(16) u8 As0[128 * 64], As1[128 * 64];  // 8 KB each
  __shared__ __align__(16) u8 Bs0[128 * 64], Bs1[128 * 64];
  int tid = threadIdx.x;
  int lane = tid & 63, wave = tid >> 6;
  int wm = wave & 1, wn = wave >> 1;
  long arow0 = (long)blockIdx.y * 128;
  long brow0 = (long)blockIdx.x * 128;
  int m_lane = lane & 31, q4 = lane >> 5;
  f32x16 acc[2][2] = {};

  g2f8_stage(A, Bt, arow0, brow0, 0, wave, lane, As0, Bs0);
  __syncthreads();

  for (int it = 0; it < 32; it += 2) {
    {
      v2i64 af[2][2], bfr[2][2];
#pragma unroll
      for (int p = 0; p < 2; p++) {
#pragma unroll
        for (int mt = 0; mt < 2; mt++)
          af[p][mt] = *(const v2i64*)(As0 + swz32(wm * 64 + mt * 32 + m_lane, p * 2 + q4) * 16);
#pragma unroll
        for (int nt = 0; nt < 2; nt++)
          bfr[p][nt] = *(const v2i64*)(Bs0 + swz32(wn * 64 + nt * 32 + m_lane, p * 2 + q4) * 16);
      }
      g2f8_stage(A, Bt, arow0, brow0, (it + 1) * 64, wave, lane, As1, Bs1);
#pragma unroll
      for (int p = 0; p < 2; p++)
#pragma unroll
        for (int mt = 0; mt < 2; mt++)
#pragma unroll
          for (int nt = 0; nt < 2; nt++) {
            acc[mt][nt] = __builtin_amdgcn_mfma_f32_32x32x16_fp8_fp8(bfr[p][nt][0], af[p][mt][0], acc[mt][nt], 0, 0, 0);
            acc[mt][nt] = __builtin_amdgcn_mfma_f32_32x32x16_fp8_fp8(bfr[p][nt][1], af[p][mt][1], acc[mt][nt], 0, 0, 0);
          }
      __syncthreads();
    }
    {
      v2i64 af[2][2], bfr[2][2];
#pragma unroll
      for (int p = 0; p < 2; p++) {
#pragma unroll
        for (int mt = 0; mt < 2; mt++)
          af[p][mt] = *(const v2i64*)(As1 + swz32(wm * 64 + mt * 32 + m_lane, p * 2 + q4) * 16);
#pragma unroll
        for (int nt = 0; nt < 2; nt++)
          bfr[p][nt] = *(const v2i64*)(Bs1 + swz32(wn * 64 + nt * 32 + m_lane, p * 2 + q4) * 16);
      }
      if (it + 2 < 32)
        g2f8_stage(A, Bt, arow0, brow0, (it + 2) * 64, wave, lane, As0, Bs0);
#pragma unroll
      for (int p = 0; p < 2; p++)
#pragma unroll
        for (int mt = 0; mt < 2; mt++)
#pragma unroll
          for (int nt = 0; nt < 2; nt++) {
            acc[mt][nt] = __builtin_amdgcn_mfma_f32_32x32x16_fp8_fp8(bfr[p][nt][0], af[p][mt][0], acc[mt][nt], 0, 0, 0);
            acc[mt][nt] = __builtin_amdgcn_mfma_f32_32x32x16_fp8_fp8(bfr[p][nt][1], af[p][mt][1], acc[mt][nt], 0, 0, 0);
          }
      __syncthreads();
    }
  }
  // token = arow0 + wm*64 + mt*32 + m_lane; ycol = brow0 + wn*64 + nt*32 + g*8 + q4*4 + j
#pragma unroll
  for (int mt = 0; mt < 2; mt++) {
    long row = arow0 + wm * 64 + mt * 32 + m_lane;
#pragma unroll
    for (int nt = 0; nt < 2; nt++) {
#pragma unroll
      for (int g = 0; g < 4; g++) {
        long col = brow0 + wn * 64 + nt * 32 + g * 8 + q4 * 4;
        float4 rv = *(const float4*)(resid + row * DIMS + col);
        float4 ov;
        ov.x = acc[mt][nt][g * 4 + 0] * INV_SCALE + rv.x;
        ov.y = acc[mt][nt][g * 4 + 1] * INV_SCALE + rv.y;
        ov.z = acc[mt][nt][g * 4 + 2] * INV_SCALE + rv.z;
        ov.w = acc[mt][nt][g * 4 + 3] * INV_SCALE + rv.w;
        *(float4*)(C + row * DIMS + col) = ov;
      }
    }
  }
}

// ---------------- chunked gated linear scan (INTERLEAVED C1, R9 form) ----------------
// C1 row layout: [ch*4+0]=Kraw, +1=uraw, +2=gin, +3=gout -> one uint2 per (ch,t).
__global__ __launch_bounds__(256) void chunk_summary_kernel(
    const bf16* __restrict__ C1, float* __restrict__ carryA,
    float* __restrict__ carryU) {
  int b = blockIdx.x;
  int ch = blockIdx.y * 256 + threadIdx.x;
  int chunk = blockIdx.z;
  int t0 = chunk * CHUNKL;
  const bf16* base = C1 + ((long)b * SEQ) * N1 + ch * 4;
  float kp = 0.0f;
  if (chunk != 0) kp = __bfloat162float(base[(long)(t0 - 1) * N1]);
  float a_first = (chunk == 0) ? 1.0f : sigmoidf_(kp);
  float A = 1.0f, U = 0.0f;
#pragma unroll 8
  for (int t = t0; t < t0 + CHUNKL; t++) {
    union { uint2 u2; u16 h[4]; } w;
    w.u2 = *(const uint2*)(base + (long)t * N1);
    float kraw = b2f(w.h[0]);
    float uraw = b2f(w.h[1]);
    float gin  = b2f(w.h[2]);
    float a = (t == t0) ? a_first : sigmoidf_(kp);
    float sK = sigmoidf_(kraw);
    float u = uraw * sigmoidf_(gin) * (1.0f - sK);
    A *= a;
    U = a * U + u;
    kp = kraw;
  }
  int cidx = (b * NCHUNK + chunk) * STATE + ch;
  carryA[cidx] = A;
  carryU[cidx] = U;
}

__global__ __launch_bounds__(256) void carry_scan_kernel(
    const float* __restrict__ carryA, const float* __restrict__ carryU,
    float* __restrict__ carryIn) {
  int idx = blockIdx.x * 256 + threadIdx.x;  // b*STATE + ch
  int b = idx >> 11;
  int ch = idx & 2047;
  float h = 0.0f;
#pragma unroll
  for (int c = 0; c < NCHUNK; c++) {
    int cidx = (b * NCHUNK + c) * STATE + ch;
    carryIn[cidx] = h;
    h = carryA[cidx] * h + carryU[cidx];
  }
}

// Pass C: local scan; writes h*sigmoid(g_out) as fp8*H_SCALE, k-permuted for GEMM2.
__global__ __launch_bounds__(256) void scan_chunk_kernel(
    const bf16* __restrict__ C1, const float* __restrict__ carryIn,
    u8* __restrict__ sco8) {
  int b = blockIdx.x;
  int c0 = blockIdx.y * 32;
  int chunk = blockIdx.z;
  int tstart = chunk * CHUNKL;
  __shared__ float a_s[32][65], u_s[32][65], h_s[32][65];
  int tid = threadIdx.x;
  int lane = tid & 63, wave = tid >> 6;
  int cc = tid & 31;
  int tq = tid >> 5;

  float carryH[8], carryK[8];
#pragma unroll
  for (int i = 0; i < 8; i++) {
    int ch = c0 + wave * 8 + i;
    carryH[i] = carryIn[(b * NCHUNK + chunk) * STATE + ch];
    carryK[i] = (chunk == 0)
                    ? 1.0f
                    : sigmoidf_(__bfloat162float(
                          C1[((long)(b * SEQ + tstart - 1)) * N1 + ch * 4]));
  }

  float g_r[8];
  for (int t0 = tstart; t0 < tstart + CHUNKL; t0 += 64) {
#pragma unroll
    for (int i = 0; i < 8; i++) {
      int t = tq * 8 + i;
      union { uint2 u2; u16 h[4]; } w;
      w.u2 = *(const uint2*)(C1 + ((long)(b * SEQ + t0 + t)) * N1 + (c0 + cc) * 4);
      float kraw = b2f(w.h[0]);
      float uraw = b2f(w.h[1]);
      float gin  = b2f(w.h[2]);
      float gout = b2f(w.h[3]);
      float aK = sigmoidf_(kraw);
      a_s[cc][t] = aK;
      u_s[cc][t] = uraw * sigmoidf_(gin) * (1.0f - aK);
      g_r[i] = sigmoidf_(gout);
    }
    __syncthreads();
#pragma unroll
    for (int i = 0; i < 8; i++) {
      int ch = wave * 8 + i;
      float aK = a_s[ch][lane];
      float u = u_s[ch][lane];
      float a = __shfl_up(aK, 1);
      if (lane == 0) a = carryK[i];
      float A = a, U = u;
#pragma unroll
      for (int d = 1; d < 64; d <<= 1) {
        float Au = __shfl_up(A, d);
        float Uu = __shfl_up(U, d);
        if (lane >= d) { U += A * Uu; A *= Au; }
      }
      float h = U + A * carryH[i];
      carryH[i] = __shfl(h, 63);
      carryK[i] = __shfl(aK, 63);
      h_s[ch][lane] = h;
    }
    __syncthreads();
#pragma unroll
    for (int i = 0; i < 8; i++) {
      int t = tq * 8 + i;
      sco8[((long)(b * SEQ + t0 + t)) * STATE + c0 + kperm(cc)] =
          to_fp8(h_s[cc][t] * g_r[i] * H_SCALE);
    }
    __syncthreads();
  }
}

extern "C" void kernel_launch(void* const* d_in, const int* in_sizes, int n_in,
                              void* d_out, int out_size, void* d_ws, size_t ws_size,
                              hipStream_t stream) {
  const float* x    = (const float*)d_in[0];
  const float* ls   = (const float*)d_in[1];
  const float* rs   = (const float*)d_in[2];
  const float* ss   = (const float*)d_in[3];
  const float* Wk   = (const float*)d_in[4];
  const float* Wugg = (const float*)d_in[5];
  const float* Wout = (const float*)d_in[6];
  float* out = (float*)d_out;

  // workspace layout (~170 MB)
  char* ws = (char*)d_ws;
  u8*   W1f8 = (u8*)ws;                                     // [8192][1024] fp8 = 8 MB (interleaved)
  u8*   W2f8 = (u8*)(ws + 8388608);                         // [1024][2048] fp8 = 2 MB
  u8*   xn8  = (u8*)(ws + 8388608 + 2097152);               // [8192][1024] fp8 = 8 MB
  bf16* C1   = (bf16*)(ws + 18874368);                      // [8192][8192] bf16 = 134 MB
  u8*   sco8 = (u8*)(ws + 18874368 + 134217728);            // [8192][2048] fp8 = 16.7 MB
  // carry buffers (3 x 512 KB) overlay xn8: xn8 is dead after gemm1.
  float* carryA  = (float*)xn8;
  float* carryU  = carryA + BATCH * NCHUNK * STATE;
  float* carryIn = carryU + BATCH * NCHUNK * STATE;

  // W1 -> fp8 (scaled, k-permuted, channel-interleaved rows); W2 -> fp8 (plain rows)
  transpose_fp8_kernel<<<dim3(STATE / 32, DIMS / 32), 256, 0, stream>>>(
      Wk, W1f8, DIMS, STATE, 0, 1, W1_SCALE);
  transpose_fp8_kernel<<<dim3(3 * STATE / 32, DIMS / 32), 256, 0, stream>>>(
      Wugg, W1f8, DIMS, 3 * STATE, 1, 1, W1_SCALE);
  transpose_fp8_kernel<<<dim3(DIMS / 32, STATE / 32), 256, 0, stream>>>(
      Wout, W2f8, STATE, DIMS, 0, 0, W2_SCALE);

  rmsnorm_kernel<<<TOKENS, 256, 0, stream>>>(x, ls, rs, ss, xn8);

  gemm1_fp8<<<dim3(N1 / 128, TOKENS / 256), 256, 0, stream>>>(xn8, W1f8, C1);

  chunk_summary_kernel<<<dim3(BATCH, STATE / 256, NCHUNK), 256, 0, stream>>>(
      C1, carryA, carryU);
  carry_scan_kernel<<<dim3(BATCH * STATE / 256), 256, 0, stream>>>(
      carryA, carryU, carryIn);
  scan_chunk_kernel<<<dim3(BATCH, STATE / 32, NCHUNK), 256, 0, stream>>>(
      C1, carryIn, sco8);

  gemm2_fp8<<<dim3(DIMS / 128, TOKENS / 128), 256, 0, stream>>>(
      sco8, W2f8, out, x);
}